// Round 1
// baseline (396.395 us; speedup 1.0000x reference)
//
#include <hip/hip_runtime.h>
#include <cstdint>
#include <cstddef>

typedef short bf16x8 __attribute__((ext_vector_type(8)));
typedef float f32x4 __attribute__((ext_vector_type(4)));
typedef unsigned short u16;
typedef u16 u16x8 __attribute__((ext_vector_type(8)));

#define GLD16(gptr, lptr)                                                            \
  __builtin_amdgcn_global_load_lds((const __attribute__((address_space(1))) void*)(gptr), \
                                   (__attribute__((address_space(3))) void*)(lptr), 16, 0, 0)

__device__ __forceinline__ u16 f2bf(float f) {
  union { float f; unsigned u; } v; v.f = f;
  unsigned r = v.u + 0x7FFF + ((v.u >> 16) & 1);
  return (u16)(r >> 16);
}
__device__ __forceinline__ float bf2f(u16 h) {
  union { unsigned u; float f; } v; v.u = ((unsigned)h) << 16;
  return v.f;
}

// read 8 contiguous bf16 from a [rows][64] bf16 LDS tile with XOR swizzle
__device__ __forceinline__ bf16x8 lds_read_sw64(const u16* base, int row, int col) {
  int byt = row * 128 + col * 2;
  byt ^= (row & 7) << 4;
  return *(const bf16x8*)((const char*)base + byt);
}

// ---------------------------------------------------------------------------
// Weight transpose + cast: out[c][r] = bf16(in[r][c]); R,C multiples of 32
// ---------------------------------------------------------------------------
__global__ __launch_bounds__(256) void transpose_cast(const float* __restrict__ in,
                                                      u16* __restrict__ out, int R, int C) {
  __shared__ float tile[32][33];
  const int tx = threadIdx.x, ty = threadIdx.y;
  const int c0 = blockIdx.x * 32, r0 = blockIdx.y * 32;
#pragma unroll
  for (int i = 0; i < 32; i += 8)
    tile[ty + i][tx] = in[(size_t)(r0 + ty + i) * C + c0 + tx];
  __syncthreads();
#pragma unroll
  for (int i = 0; i < 32; i += 8)
    out[(size_t)(c0 + ty + i) * R + r0 + tx] = f2bf(tile[tx][ty + i]);
}

// ---------------------------------------------------------------------------
// LayerNorm (D=1024): fp32 in -> bf16 out
// ---------------------------------------------------------------------------
__global__ __launch_bounds__(256) void layernorm_bf16(const float* __restrict__ X,
                                                      const float* __restrict__ g,
                                                      const float* __restrict__ be,
                                                      u16* __restrict__ out) {
  const int row = blockIdx.x, t = threadIdx.x;
  const int lane = t & 63, wave = t >> 6;
  const float* x = X + (size_t)row * 1024;
  __shared__ float part[4];
  float v[4]; float s = 0.f;
#pragma unroll
  for (int i = 0; i < 4; ++i) { v[i] = x[t + i * 256]; s += v[i]; }
#pragma unroll
  for (int o = 32; o >= 1; o >>= 1) s += __shfl_xor(s, o);
  if (lane == 0) part[wave] = s;
  __syncthreads();
  const float mu = (part[0] + part[1] + part[2] + part[3]) * (1.f / 1024.f);
  float d2 = 0.f;
#pragma unroll
  for (int i = 0; i < 4; ++i) { float d = v[i] - mu; d2 += d * d; }
#pragma unroll
  for (int o = 32; o >= 1; o >>= 1) d2 += __shfl_xor(d2, o);
  __syncthreads();
  if (lane == 0) part[wave] = d2;
  __syncthreads();
  const float var = (part[0] + part[1] + part[2] + part[3]) * (1.f / 1024.f);
  const float rstd = rsqrtf(var + 1e-5f);
#pragma unroll
  for (int i = 0; i < 4; ++i) {
    const int c = t + i * 256;
    out[(size_t)row * 1024 + c] = f2bf((v[i] - mu) * rstd * g[c] + be[c]);
  }
}

// ---------------------------------------------------------------------------
// Generic bf16 MFMA GEMM: C[M,N] = A[M,K] * Bt[N,K]^T + bias (+epilogue)
// EPI 0: bf16 out; EPI 1: f32 out = res + acc + bias; EPI 2: bf16 gelu(acc+bias)
// M%128==0, N%128==0, K%64==0
// ---------------------------------------------------------------------------
template <int EPI>
__global__ __launch_bounds__(256) void gemm_bf16(const u16* __restrict__ A,
                                                 const u16* __restrict__ Bt,
                                                 const float* __restrict__ bias,
                                                 const float* __restrict__ res,
                                                 float* __restrict__ outf,
                                                 u16* __restrict__ outb,
                                                 int M, int N, int K) {
  __shared__ u16 As[128 * 64];
  __shared__ u16 Bs[128 * 64];
  const int t = threadIdx.x, lane = t & 63, wave = t >> 6;
  const int bm = blockIdx.y * 128, bn = blockIdx.x * 128;
  const int wm = (wave >> 1) * 64, wn = (wave & 1) * 64;
  f32x4 acc[4][4] = {};

  int srow[4], scol[4];
#pragma unroll
  for (int is = 0; is < 4; ++is) {
    int L = (is * 2048 + t * 8) * 2;
    int x = (L ^ ((L >> 3) & 0x70)) >> 1;   // pre-swizzled source element
    srow[is] = x >> 6; scol[is] = x & 63;
  }

  for (int kt = 0; kt < K; kt += 64) {
#pragma unroll
    for (int is = 0; is < 4; ++is) {
      const u16* gp = A + (size_t)(bm + srow[is]) * K + kt + scol[is];
      GLD16(gp, (char*)As + is * 4096 + wave * 1024);
    }
#pragma unroll
    for (int is = 0; is < 4; ++is) {
      const u16* gp = Bt + (size_t)(bn + srow[is]) * K + kt + scol[is];
      GLD16(gp, (char*)Bs + is * 4096 + wave * 1024);
    }
    __syncthreads();
#pragma unroll
    for (int ks = 0; ks < 2; ++ks) {
      bf16x8 af[4], bfr[4];
#pragma unroll
      for (int m = 0; m < 4; ++m)
        af[m] = lds_read_sw64(As, wm + m * 16 + (lane & 15), ks * 32 + (lane >> 4) * 8);
#pragma unroll
      for (int n = 0; n < 4; ++n)
        bfr[n] = lds_read_sw64(Bs, wn + n * 16 + (lane & 15), ks * 32 + (lane >> 4) * 8);
#pragma unroll
      for (int m = 0; m < 4; ++m)
#pragma unroll
        for (int n = 0; n < 4; ++n)
          acc[m][n] = __builtin_amdgcn_mfma_f32_16x16x32_bf16(af[m], bfr[n], acc[m][n], 0, 0, 0);
    }
    __syncthreads();
  }

  const int r0 = (lane >> 4) * 4, cc = lane & 15;
#pragma unroll
  for (int m = 0; m < 4; ++m) {
#pragma unroll
    for (int n = 0; n < 4; ++n) {
      const int col = bn + wn + n * 16 + cc;
      const float bv = bias[col];
#pragma unroll
      for (int r = 0; r < 4; ++r) {
        const int row = bm + wm + m * 16 + r0 + r;
        const float v = acc[m][n][r] + bv;
        const size_t o = (size_t)row * N + col;
        if (EPI == 0) {
          outb[o] = f2bf(v);
        } else if (EPI == 1) {
          outf[o] = res[o] + v;
        } else {
          const float gl = 0.5f * v * (1.0f + erff(v * 0.70710678118654752f));
          outb[o] = f2bf(gl);
        }
      }
    }
  }
}

// ---------------------------------------------------------------------------
// Attention scores + softmax -> probs (bf16). grid(4 qblk, 16 h, 32 b), 256 thr
// probs layout: [b][h][q][k] = [((b*16+h)*256+q)*256+k]
// ---------------------------------------------------------------------------
__global__ __launch_bounds__(256) void attn_scores(const u16* __restrict__ qkv,
                                                   u16* __restrict__ probs) {
  __shared__ u16 Ks[256 * 64];  // 32KB swizzled
  __shared__ u16 Qs[64 * 64];   //  8KB swizzled
  const int t = threadIdx.x, lane = t & 63, wave = t >> 6;
  const int qb = blockIdx.x * 64, h = blockIdx.y, b = blockIdx.z;
  const size_t row0 = (size_t)b * 256 * 3072;

#pragma unroll
  for (int is = 0; is < 8; ++is) {
    int L = (is * 2048 + t * 8) * 2;
    int x = (L ^ ((L >> 3) & 0x70)) >> 1;
    int kk = x >> 6, d = x & 63;
    const u16* gp = qkv + row0 + (size_t)kk * 3072 + 1024 + h * 64 + d;
    GLD16(gp, (char*)Ks + is * 4096 + wave * 1024);
  }
#pragma unroll
  for (int is = 0; is < 2; ++is) {
    int L = (is * 2048 + t * 8) * 2;
    int x = (L ^ ((L >> 3) & 0x70)) >> 1;
    int q = x >> 6, d = x & 63;
    const u16* gp = qkv + row0 + (size_t)(qb + q) * 3072 + h * 64 + d;
    GLD16(gp, (char*)Qs + is * 4096 + wave * 1024);
  }
  __syncthreads();

  f32x4 acc[16] = {};
  bf16x8 aq[2];
#pragma unroll
  for (int ks = 0; ks < 2; ++ks)
    aq[ks] = lds_read_sw64(Qs, wave * 16 + (lane & 15), ks * 32 + (lane >> 4) * 8);
#pragma unroll
  for (int nf = 0; nf < 16; ++nf) {
#pragma unroll
    for (int ks = 0; ks < 2; ++ks) {
      bf16x8 bk = lds_read_sw64(Ks, nf * 16 + (lane & 15), ks * 32 + (lane >> 4) * 8);
      acc[nf] = __builtin_amdgcn_mfma_f32_16x16x32_bf16(aq[ks], bk, acc[nf], 0, 0, 0);
    }
  }

  const int r0 = (lane >> 4) * 4, cc = lane & 15;
  const float sc = 0.125f;  // 1/sqrt(64)
#pragma unroll
  for (int r = 0; r < 4; ++r) {
    float mx = -1e30f;
#pragma unroll
    for (int nf = 0; nf < 16; ++nf) mx = fmaxf(mx, acc[nf][r]);
#pragma unroll
    for (int o = 8; o >= 1; o >>= 1) mx = fmaxf(mx, __shfl_xor(mx, o));
    float s = 0.f;
#pragma unroll
    for (int nf = 0; nf < 16; ++nf) {
      float e = __expf((acc[nf][r] - mx) * sc);
      acc[nf][r] = e; s += e;
    }
#pragma unroll
    for (int o = 8; o >= 1; o >>= 1) s += __shfl_xor(s, o);
    const float rinv = 1.f / s;
    const int qrow = qb + wave * 16 + r0 + r;
    u16* prow = probs + (size_t)((b * 16 + h) * 256 + qrow) * 256;
#pragma unroll
    for (int nf = 0; nf < 16; ++nf)
      prow[nf * 16 + cc] = f2bf(acc[nf][r] * rinv);
  }
}

// ---------------------------------------------------------------------------
// A = mean over heads of probs. grid(8192=b*256+q), 256 thr
// ---------------------------------------------------------------------------
__global__ __launch_bounds__(256) void amean(const u16* __restrict__ probs,
                                             float* __restrict__ A) {
  const int bq = blockIdx.x;
  const int b = bq >> 8, q = bq & 255;
  const int t = threadIdx.x;
  float s = 0.f;
#pragma unroll
  for (int h = 0; h < 16; ++h)
    s += bf2f(probs[(size_t)((b * 16 + h) * 256 + q) * 256 + t]);
  A[(size_t)bq * 256 + t] = s * (1.f / 16.f);
}

// ---------------------------------------------------------------------------
// PV: ctx[b,:,h*64:+64] = probs[b,h] @ V[b,h]. grid(16 h, 32 b), 256 thr
// ---------------------------------------------------------------------------
__global__ __launch_bounds__(256) void attn_pv(const u16* __restrict__ qkv,
                                               const u16* __restrict__ probs,
                                               u16* __restrict__ ctx) {
  __shared__ u16 Vs[64 * 256];  // 32KB: [d][kk], swizzled
  const int t = threadIdx.x, lane = t & 63, wave = t >> 6;
  const int h = blockIdx.x, b = blockIdx.y;

#pragma unroll
  for (int p = 0; p < 8; ++p) {
    int idx = p * 2048 + t * 8;
    int kk = idx >> 6, d0 = idx & 63;
    u16x8 vv = *(const u16x8*)(qkv + (size_t)(b * 256 + kk) * 3072 + 2048 + h * 64 + d0);
#pragma unroll
    for (int j = 0; j < 8; ++j) {
      int d = d0 + j;
      int byt = (d * 512 + kk * 2) ^ ((d & 7) << 4);
      *(u16*)((char*)Vs + byt) = vv[j];
    }
  }
  __syncthreads();

  f32x4 acc[4][4] = {};
  const u16* Pb = probs + (size_t)((b * 16 + h) * 256) * 256;
  const int cc = lane & 15, kg = (lane >> 4) * 8;
#pragma unroll
  for (int kt = 0; kt < 8; ++kt) {
    bf16x8 a[4], v[4];
#pragma unroll
    for (int m = 0; m < 4; ++m)
      a[m] = *(const bf16x8*)(Pb + (size_t)(wave * 64 + m * 16 + cc) * 256 + kt * 32 + kg);
#pragma unroll
    for (int n = 0; n < 4; ++n) {
      int d = n * 16 + cc;
      int kk = kt * 32 + kg;
      int byt = (d * 512 + kk * 2) ^ ((d & 7) << 4);
      v[n] = *(const bf16x8*)((const char*)Vs + byt);
    }
#pragma unroll
    for (int m = 0; m < 4; ++m)
#pragma unroll
      for (int n = 0; n < 4; ++n)
        acc[m][n] = __builtin_amdgcn_mfma_f32_16x16x32_bf16(a[m], v[n], acc[m][n], 0, 0, 0);
  }

  const int r0 = (lane >> 4) * 4;
#pragma unroll
  for (int m = 0; m < 4; ++m) {
    const int q = wave * 64 + m * 16 + r0;
#pragma unroll
    for (int n = 0; n < 4; ++n) {
      const int col = h * 64 + n * 16 + cc;
#pragma unroll
      for (int r = 0; r < 4; ++r)
        ctx[(size_t)(b * 256 + q + r) * 1024 + col] = f2bf(acc[m][n][r]);
    }
  }
}

// ---------------------------------------------------------------------------
extern "C" void kernel_launch(void* const* d_in, const int* in_sizes, int n_in,
                              void* d_out, int out_size, void* d_ws, size_t ws_size,
                              hipStream_t stream) {
  const float* X      = (const float*)d_in[0];
  const float* W_qkv  = (const float*)d_in[1];
  const float* b_qkv  = (const float*)d_in[2];
  const float* W_proj = (const float*)d_in[3];
  const float* b_proj = (const float*)d_in[4];
  const float* g1     = (const float*)d_in[5];
  const float* beta1  = (const float*)d_in[6];
  const float* g2     = (const float*)d_in[7];
  const float* beta2  = (const float*)d_in[8];
  const float* W_ff1  = (const float*)d_in[9];
  const float* b_ff1  = (const float*)d_in[10];
  const float* W_ff2  = (const float*)d_in[11];
  const float* b_ff2  = (const float*)d_in[12];

  float* Xout = (float*)d_out;                 // [8192][1024]
  float* Aout = (float*)d_out + 8388608;       // [32][256][256]

  char* ws = (char*)d_ws;
  const size_t MB = 1u << 20;
  u16* xn    = (u16*)(ws + 0);          // 16MB: Xn, then ctx, then X1n
  u16* wqkv  = (u16*)(ws + 16 * MB);    // 6MB [3072][1024]
  u16* wproj = (u16*)(ws + 22 * MB);    // 2MB [1024][1024]
  u16* wff1  = (u16*)(ws + 24 * MB);    // 8MB [4096][1024]
  u16* wff2  = (u16*)(ws + 32 * MB);    // 8MB [1024][4096]
  u16* qkv   = (u16*)(ws + 40 * MB);    // 48MB [8192][3072]
  u16* probs = (u16*)(ws + 88 * MB);    // 64MB [32][16][256][256]; later h
  u16* hbuf  = probs;                   // 64MB [8192][4096]
  float* x1  = (float*)(ws + 152 * MB); // 32MB [8192][1024]  (total 184MB)
  u16* ctx   = xn;                      // reuse region 0 after QKV GEMM
  u16* x1n   = xn;                      // reuse region 0 after proj GEMM

  const dim3 tb(32, 8);
  transpose_cast<<<dim3(96, 32),  tb, 0, stream>>>(W_qkv,  wqkv, 1024, 3072);
  transpose_cast<<<dim3(32, 32),  tb, 0, stream>>>(W_proj, wproj, 1024, 1024);
  transpose_cast<<<dim3(128, 32), tb, 0, stream>>>(W_ff1,  wff1, 1024, 4096);
  transpose_cast<<<dim3(32, 128), tb, 0, stream>>>(W_ff2,  wff2, 4096, 1024);

  layernorm_bf16<<<8192, 256, 0, stream>>>(X, g1, beta1, xn);

  // QKV: [8192,1024]x[1024,3072] -> qkv bf16
  gemm_bf16<0><<<dim3(24, 64), 256, 0, stream>>>(xn, wqkv, b_qkv, nullptr, nullptr, qkv,
                                                 8192, 3072, 1024);

  attn_scores<<<dim3(4, 16, 32), 256, 0, stream>>>(qkv, probs);
  amean<<<8192, 256, 0, stream>>>(probs, Aout);
  attn_pv<<<dim3(16, 32), 256, 0, stream>>>(qkv, probs, ctx);

  // proj + residual: x1 = X + ctx@W_proj + b
  gemm_bf16<1><<<dim3(8, 64), 256, 0, stream>>>(ctx, wproj, b_proj, X, x1, nullptr,
                                                8192, 1024, 1024);

  layernorm_bf16<<<8192, 256, 0, stream>>>(x1, g2, beta2, x1n);

  // FF1 + GELU: h = gelu(x1n@W_ff1 + b)
  gemm_bf16<2><<<dim3(32, 64), 256, 0, stream>>>(x1n, wff1, b_ff1, nullptr, nullptr, hbuf,
                                                 8192, 4096, 1024);

  // FF2 + residual: Xout = x1 + h@W_ff2 + b
  gemm_bf16<1><<<dim3(8, 64), 256, 0, stream>>>(hbuf, wff2, b_ff2, x1, Xout, nullptr,
                                                8192, 1024, 4096);
}

// Round 2
// 380.263 us; speedup vs baseline: 1.0424x; 1.0424x over previous
//
#include <hip/hip_runtime.h>
#include <cstdint>
#include <cstddef>

typedef short bf16x8 __attribute__((ext_vector_type(8)));
typedef float f32x4 __attribute__((ext_vector_type(4)));
typedef unsigned short u16;
typedef u16 u16x8 __attribute__((ext_vector_type(8)));

#define GLD16(gptr, lptr)                                                            \
  __builtin_amdgcn_global_load_lds((const __attribute__((address_space(1))) void*)(gptr), \
                                   (__attribute__((address_space(3))) void*)(lptr), 16, 0, 0)

__device__ __forceinline__ u16 f2bf(float f) {
  union { float f; unsigned u; } v; v.f = f;
  unsigned r = v.u + 0x7FFF + ((v.u >> 16) & 1);
  return (u16)(r >> 16);
}
__device__ __forceinline__ float bf2f(u16 h) {
  union { unsigned u; float f; } v; v.u = ((unsigned)h) << 16;
  return v.f;
}

template <int N> __device__ __forceinline__ void vmwait() {
  if constexpr (N == 0) asm volatile("s_waitcnt vmcnt(0)" ::: "memory");
  else if constexpr (N == 3) asm volatile("s_waitcnt vmcnt(3)" ::: "memory");
  else if constexpr (N == 4) asm volatile("s_waitcnt vmcnt(4)" ::: "memory");
  else if constexpr (N == 6) asm volatile("s_waitcnt vmcnt(6)" ::: "memory");
  else asm volatile("s_waitcnt vmcnt(8)" ::: "memory");
}

// read 8 contiguous bf16 from a [rows][64] bf16 LDS tile with XOR swizzle (attn)
__device__ __forceinline__ bf16x8 lds_read_sw64(const u16* base, int row, int col) {
  int byt = row * 128 + col * 2;
  byt ^= (row & 7) << 4;
  return *(const bf16x8*)((const char*)base + byt);
}

// ---------------------------------------------------------------------------
// Weight transpose + cast: out[c][r] = bf16(in[r][c]); R,C multiples of 32
// ---------------------------------------------------------------------------
__global__ __launch_bounds__(256) void transpose_cast(const float* __restrict__ in,
                                                      u16* __restrict__ out, int R, int C) {
  __shared__ float tile[32][33];
  const int tx = threadIdx.x, ty = threadIdx.y;
  const int c0 = blockIdx.x * 32, r0 = blockIdx.y * 32;
#pragma unroll
  for (int i = 0; i < 32; i += 8)
    tile[ty + i][tx] = in[(size_t)(r0 + ty + i) * C + c0 + tx];
  __syncthreads();
#pragma unroll
  for (int i = 0; i < 32; i += 8)
    out[(size_t)(c0 + ty + i) * R + r0 + tx] = f2bf(tile[tx][ty + i]);
}

// ---------------------------------------------------------------------------
// LayerNorm (D=1024): fp32 in -> bf16 out
// ---------------------------------------------------------------------------
__global__ __launch_bounds__(256) void layernorm_bf16(const float* __restrict__ X,
                                                      const float* __restrict__ g,
                                                      const float* __restrict__ be,
                                                      u16* __restrict__ out) {
  const int row = blockIdx.x, t = threadIdx.x;
  const int lane = t & 63, wave = t >> 6;
  const float* x = X + (size_t)row * 1024;
  __shared__ float part[4];
  float v[4]; float s = 0.f;
#pragma unroll
  for (int i = 0; i < 4; ++i) { v[i] = x[t + i * 256]; s += v[i]; }
#pragma unroll
  for (int o = 32; o >= 1; o >>= 1) s += __shfl_xor(s, o);
  if (lane == 0) part[wave] = s;
  __syncthreads();
  const float mu = (part[0] + part[1] + part[2] + part[3]) * (1.f / 1024.f);
  float d2 = 0.f;
#pragma unroll
  for (int i = 0; i < 4; ++i) { float d = v[i] - mu; d2 += d * d; }
#pragma unroll
  for (int o = 32; o >= 1; o >>= 1) d2 += __shfl_xor(d2, o);
  __syncthreads();
  if (lane == 0) part[wave] = d2;
  __syncthreads();
  const float var = (part[0] + part[1] + part[2] + part[3]) * (1.f / 1024.f);
  const float rstd = rsqrtf(var + 1e-5f);
#pragma unroll
  for (int i = 0; i < 4; ++i) {
    const int c = t + i * 256;
    out[(size_t)row * 1024 + c] = f2bf((v[i] - mu) * rstd * g[c] + be[c]);
  }
}

// ---------------------------------------------------------------------------
// Pipelined bf16 MFMA GEMM: C[M,N] = A[M,K] * Bt[N,K]^T + bias (+epilogue)
// BK=32, 4-deep LDS ring, counted vmcnt, raw barriers (1 per K-step).
// EPI 0: bf16 out; EPI 1: f32 out = res + acc + bias; EPI 2: bf16 gelu(acc+bias)
// BM = WM*MF*16 (=256), BN = WN*NF*16; M%BM==0, N%BN==0, K%32==0, K>=96
// ---------------------------------------------------------------------------
template <int EPI, int WM, int WN, int MF, int NF>
__global__ __launch_bounds__(512, 2) void gemm_pipe(const u16* __restrict__ A,
                                                    const u16* __restrict__ Bt,
                                                    const float* __restrict__ bias,
                                                    const float* __restrict__ res,
                                                    float* __restrict__ outf,
                                                    u16* __restrict__ outb,
                                                    int M, int N, int K) {
  constexpr int BM = WM * MF * 16, BN = WN * NF * 16;
  constexpr int LA = BM / 128, LB = BN / 128, L = LA + LB;  // gld_lds per thread per tile
  constexpr int ASZ = BM * 32, BSZ = BN * 32;               // u16 elems per tile
  __shared__ u16 lds[4 * (ASZ + BSZ)];

  const int t = threadIdx.x, lane = t & 63, wave = t >> 6;
  const int wm = wave / WN, wn = wave % WN;
  const int l15 = lane & 15, l16 = lane >> 4;

  // XCD-chunked logical block id (gridDim.x % 8 == 0 guaranteed by launch)
  const int lb = (blockIdx.x & 7) * ((int)gridDim.x >> 3) + ((int)blockIdx.x >> 3);
  const int NBN = N / BN;
  const int bm = (lb / NBN) * BM, bn = (lb % NBN) * BN;

  // staging sources (tile 0); advance by kt*32 elems per tile
  const u16* asrcj[LA];
  const u16* bsrcj[LB];
#pragma unroll
  for (int j = 0; j < LA; ++j)
    asrcj[j] = A + (size_t)(bm + j * 128 + (t >> 2)) * K + (t & 3) * 8;
#pragma unroll
  for (int j = 0; j < LB; ++j)
    bsrcj[j] = Bt + (size_t)(bn + j * 128 + (t >> 2)) * K + (t & 3) * 8;

  auto stage = [&](int p) {
    const int koff = p * 32;
    char* abase = (char*)lds + (p & 3) * (ASZ * 2) + wave * 1024;
    char* bbase = (char*)lds + 8 * ASZ + (p & 3) * (BSZ * 2) + wave * 1024;
#pragma unroll
    for (int j = 0; j < LA; ++j) GLD16(asrcj[j] + koff, abase + j * 8192);
#pragma unroll
    for (int j = 0; j < LB; ++j) GLD16(bsrcj[j] + koff, bbase + j * 8192);
  };

  // fragment element offsets within a tile buffer ([row][32] linear; rows 64B
  // -> even/odd rows split bank halves, 2 lanes/bank = conflict-free)
  int aoff[MF], boff[NF];
#pragma unroll
  for (int m = 0; m < MF; ++m) aoff[m] = (wm * MF * 16 + m * 16 + l15) * 32 + l16 * 8;
#pragma unroll
  for (int n = 0; n < NF; ++n) boff[n] = (wn * NF * 16 + n * 16 + l15) * 32 + l16 * 8;

  const int nkt = K >> 5;
  // prologue: tiles 0..2 in flight
#pragma unroll
  for (int p = 0; p < 3; ++p) stage(p);

  f32x4 acc[MF][NF] = {};

#pragma unroll 1
  for (int kt = 0; kt < nkt; ++kt) {
    const int rem = nkt - 1 - kt;
    if (rem >= 2) vmwait<2 * L>();
    else if (rem == 1) vmwait<L>();
    else vmwait<0>();
    __builtin_amdgcn_s_barrier();
    __builtin_amdgcn_sched_barrier(0);
    if (rem >= 3) stage(kt + 3);

    const u16* ab = lds + (kt & 3) * ASZ;
    const u16* bb = lds + 4 * ASZ + (kt & 3) * BSZ;
    bf16x8 a[MF], b[NF];
#pragma unroll
    for (int m = 0; m < MF; ++m) a[m] = *(const bf16x8*)(ab + aoff[m]);
#pragma unroll
    for (int n = 0; n < NF; ++n) b[n] = *(const bf16x8*)(bb + boff[n]);
    __builtin_amdgcn_s_setprio(1);
#pragma unroll
    for (int m = 0; m < MF; ++m)
#pragma unroll
      for (int n = 0; n < NF; ++n)
        acc[m][n] = __builtin_amdgcn_mfma_f32_16x16x32_bf16(a[m], b[n], acc[m][n], 0, 0, 0);
    __builtin_amdgcn_s_setprio(0);
  }

  const int r0 = l16 * 4;
#pragma unroll
  for (int m = 0; m < MF; ++m) {
#pragma unroll
    for (int n = 0; n < NF; ++n) {
      const int col = bn + wn * NF * 16 + n * 16 + l15;
      const float bv = bias[col];
#pragma unroll
      for (int r = 0; r < 4; ++r) {
        const int row = bm + wm * MF * 16 + m * 16 + r0 + r;
        const float v = acc[m][n][r] + bv;
        const size_t o = (size_t)row * N + col;
        if (EPI == 0) {
          outb[o] = f2bf(v);
        } else if (EPI == 1) {
          outf[o] = res[o] + v;
        } else {
          // tanh-form GELU (|err| ~3e-4, well under threshold)
          const float u = 0.7978845608f * (v + 0.044715f * v * v * v);
          const float e = __expf(2.f * u);
          const float th = 1.f - 2.f / (1.f + e);
          outb[o] = f2bf(0.5f * v * (1.f + th));
        }
      }
    }
  }
}

// ---------------------------------------------------------------------------
// Attention scores + softmax -> probs (bf16). grid(4 qblk, 16 h, 32 b), 256 thr
// probs layout: [b][h][q][k] = [((b*16+h)*256+q)*256+k]
// ---------------------------------------------------------------------------
__global__ __launch_bounds__(256) void attn_scores(const u16* __restrict__ qkv,
                                                   u16* __restrict__ probs) {
  __shared__ u16 Ks[256 * 64];  // 32KB swizzled
  __shared__ u16 Qs[64 * 64];   //  8KB swizzled
  const int t = threadIdx.x, lane = t & 63, wave = t >> 6;
  const int qb = blockIdx.x * 64, h = blockIdx.y, b = blockIdx.z;
  const size_t row0 = (size_t)b * 256 * 3072;

#pragma unroll
  for (int is = 0; is < 8; ++is) {
    int L = (is * 2048 + t * 8) * 2;
    int x = (L ^ ((L >> 3) & 0x70)) >> 1;
    int kk = x >> 6, d = x & 63;
    const u16* gp = qkv + row0 + (size_t)kk * 3072 + 1024 + h * 64 + d;
    GLD16(gp, (char*)Ks + is * 4096 + wave * 1024);
  }
#pragma unroll
  for (int is = 0; is < 2; ++is) {
    int L = (is * 2048 + t * 8) * 2;
    int x = (L ^ ((L >> 3) & 0x70)) >> 1;
    int q = x >> 6, d = x & 63;
    const u16* gp = qkv + row0 + (size_t)(qb + q) * 3072 + h * 64 + d;
    GLD16(gp, (char*)Qs + is * 4096 + wave * 1024);
  }
  __syncthreads();

  f32x4 acc[16] = {};
  bf16x8 aq[2];
#pragma unroll
  for (int ks = 0; ks < 2; ++ks)
    aq[ks] = lds_read_sw64(Qs, wave * 16 + (lane & 15), ks * 32 + (lane >> 4) * 8);
#pragma unroll
  for (int nf = 0; nf < 16; ++nf) {
#pragma unroll
    for (int ks = 0; ks < 2; ++ks) {
      bf16x8 bk = lds_read_sw64(Ks, nf * 16 + (lane & 15), ks * 32 + (lane >> 4) * 8);
      acc[nf] = __builtin_amdgcn_mfma_f32_16x16x32_bf16(aq[ks], bk, acc[nf], 0, 0, 0);
    }
  }

  const int r0 = (lane >> 4) * 4, cc = lane & 15;
  const float sc = 0.125f;  // 1/sqrt(64)
#pragma unroll
  for (int r = 0; r < 4; ++r) {
    float mx = -1e30f;
#pragma unroll
    for (int nf = 0; nf < 16; ++nf) mx = fmaxf(mx, acc[nf][r]);
#pragma unroll
    for (int o = 8; o >= 1; o >>= 1) mx = fmaxf(mx, __shfl_xor(mx, o));
    float s = 0.f;
#pragma unroll
    for (int nf = 0; nf < 16; ++nf) {
      float e = __expf((acc[nf][r] - mx) * sc);
      acc[nf][r] = e; s += e;
    }
#pragma unroll
    for (int o = 8; o >= 1; o >>= 1) s += __shfl_xor(s, o);
    const float rinv = 1.f / s;
    const int qrow = qb + wave * 16 + r0 + r;
    u16* prow = probs + (size_t)((b * 16 + h) * 256 + qrow) * 256;
#pragma unroll
    for (int nf = 0; nf < 16; ++nf)
      prow[nf * 16 + cc] = f2bf(acc[nf][r] * rinv);
  }
}

// ---------------------------------------------------------------------------
// A = mean over heads of probs. grid(8192=b*256+q), 256 thr
// ---------------------------------------------------------------------------
__global__ __launch_bounds__(256) void amean(const u16* __restrict__ probs,
                                             float* __restrict__ A) {
  const int bq = blockIdx.x;
  const int b = bq >> 8, q = bq & 255;
  const int t = threadIdx.x;
  float s = 0.f;
#pragma unroll
  for (int h = 0; h < 16; ++h)
    s += bf2f(probs[(size_t)((b * 16 + h) * 256 + q) * 256 + t]);
  A[(size_t)bq * 256 + t] = s * (1.f / 16.f);
}

// ---------------------------------------------------------------------------
// PV: ctx[b,:,h*64:+64] = probs[b,h] @ V[b,h]. grid(16 h, 32 b), 256 thr
// ---------------------------------------------------------------------------
__global__ __launch_bounds__(256) void attn_pv(const u16* __restrict__ qkv,
                                               const u16* __restrict__ probs,
                                               u16* __restrict__ ctx) {
  __shared__ u16 Vs[64 * 256];  // 32KB: [d][kk], swizzled
  const int t = threadIdx.x, lane = t & 63, wave = t >> 6;
  const int h = blockIdx.x, b = blockIdx.y;

#pragma unroll
  for (int p = 0; p < 8; ++p) {
    int idx = p * 2048 + t * 8;
    int kk = idx >> 6, d0 = idx & 63;
    u16x8 vv = *(const u16x8*)(qkv + (size_t)(b * 256 + kk) * 3072 + 2048 + h * 64 + d0);
#pragma unroll
    for (int j = 0; j < 8; ++j) {
      int d = d0 + j;
      int byt = (d * 512 + kk * 2) ^ ((d & 7) << 4);
      *(u16*)((char*)Vs + byt) = vv[j];
    }
  }
  __syncthreads();

  f32x4 acc[4][4] = {};
  const u16* Pb = probs + (size_t)((b * 16 + h) * 256) * 256;
  const int cc = lane & 15, kg = (lane >> 4) * 8;
#pragma unroll
  for (int kt = 0; kt < 8; ++kt) {
    bf16x8 a[4], v[4];
#pragma unroll
    for (int m = 0; m < 4; ++m)
      a[m] = *(const bf16x8*)(Pb + (size_t)(wave * 64 + m * 16 + cc) * 256 + kt * 32 + kg);
#pragma unroll
    for (int n = 0; n < 4; ++n) {
      int d = n * 16 + cc;
      int kk = kt * 32 + kg;
      int byt = (d * 512 + kk * 2) ^ ((d & 7) << 4);
      v[n] = *(const bf16x8*)((const char*)Vs + byt);
    }
#pragma unroll
    for (int m = 0; m < 4; ++m)
#pragma unroll
      for (int n = 0; n < 4; ++n)
        acc[m][n] = __builtin_amdgcn_mfma_f32_16x16x32_bf16(a[m], v[n], acc[m][n], 0, 0, 0);
  }

  const int r0 = (lane >> 4) * 4;
#pragma unroll
  for (int m = 0; m < 4; ++m) {
    const int q = wave * 64 + m * 16 + r0;
#pragma unroll
    for (int n = 0; n < 4; ++n) {
      const int col = h * 64 + n * 16 + cc;
#pragma unroll
      for (int r = 0; r < 4; ++r)
        ctx[(size_t)(b * 256 + q + r) * 1024 + col] = f2bf(acc[m][n][r]);
    }
  }
}

// ---------------------------------------------------------------------------
extern "C" void kernel_launch(void* const* d_in, const int* in_sizes, int n_in,
                              void* d_out, int out_size, void* d_ws, size_t ws_size,
                              hipStream_t stream) {
  const float* X      = (const float*)d_in[0];
  const float* W_qkv  = (const float*)d_in[1];
  const float* b_qkv  = (const float*)d_in[2];
  const float* W_proj = (const float*)d_in[3];
  const float* b_proj = (const float*)d_in[4];
  const float* g1     = (const float*)d_in[5];
  const float* beta1  = (const float*)d_in[6];
  const float* g2     = (const float*)d_in[7];
  const float* beta2  = (const float*)d_in[8];
  const float* W_ff1  = (const float*)d_in[9];
  const float* b_ff1  = (const float*)d_in[10];
  const float* W_ff2  = (const float*)d_in[11];
  const float* b_ff2  = (const float*)d_in[12];

  float* Xout = (float*)d_out;                 // [8192][1024]
  float* Aout = (float*)d_out + 8388608;       // [32][256][256]

  char* ws = (char*)d_ws;
  const size_t MB = 1u << 20;
  u16* xn    = (u16*)(ws + 0);          // 16MB: Xn, then ctx, then X1n
  u16* wqkv  = (u16*)(ws + 16 * MB);    // 6MB [3072][1024]
  u16* wproj = (u16*)(ws + 22 * MB);    // 2MB [1024][1024]
  u16* wff1  = (u16*)(ws + 24 * MB);    // 8MB [4096][1024]
  u16* wff2  = (u16*)(ws + 32 * MB);    // 8MB [1024][4096]
  u16* qkv   = (u16*)(ws + 40 * MB);    // 48MB [8192][3072]
  u16* probs = (u16*)(ws + 88 * MB);    // 64MB [32][16][256][256]; later h
  u16* hbuf  = probs;                   // 64MB [8192][4096]
  float* x1  = (float*)(ws + 152 * MB); // 32MB [8192][1024]  (total 184MB)
  u16* ctx   = xn;                      // reuse region 0 after QKV GEMM
  u16* x1n   = xn;                      // reuse region 0 after proj GEMM

  const dim3 tb(32, 8);
  transpose_cast<<<dim3(96, 32),  tb, 0, stream>>>(W_qkv,  wqkv, 1024, 3072);
  transpose_cast<<<dim3(32, 32),  tb, 0, stream>>>(W_proj, wproj, 1024, 1024);
  transpose_cast<<<dim3(128, 32), tb, 0, stream>>>(W_ff1,  wff1, 1024, 4096);
  transpose_cast<<<dim3(32, 128), tb, 0, stream>>>(W_ff2,  wff2, 4096, 1024);

  layernorm_bf16<<<8192, 256, 0, stream>>>(X, g1, beta1, xn);

  // QKV: [8192,1024]x[1024,3072] -> qkv bf16. Config B (256x128), 768 blocks.
  gemm_pipe<0, 4, 2, 4, 4><<<768, 512, 0, stream>>>(xn, wqkv, b_qkv, nullptr, nullptr, qkv,
                                                    8192, 3072, 1024);

  attn_scores<<<dim3(4, 16, 32), 256, 0, stream>>>(qkv, probs);
  amean<<<8192, 256, 0, stream>>>(probs, Aout);
  attn_pv<<<dim3(16, 32), 256, 0, stream>>>(qkv, probs, ctx);

  // proj + residual: x1 = X + ctx@W_proj + b. Config B, 256 blocks.
  gemm_pipe<1, 4, 2, 4, 4><<<256, 512, 0, stream>>>(ctx, wproj, b_proj, X, x1, nullptr,
                                                    8192, 1024, 1024);

  layernorm_bf16<<<8192, 256, 0, stream>>>(x1, g2, beta2, x1n);

  // FF1 + GELU: h = gelu(x1n@W_ff1 + b). Config A (256x256), 512 blocks.
  gemm_pipe<2, 2, 4, 8, 4><<<512, 512, 0, stream>>>(x1n, wff1, b_ff1, nullptr, nullptr, hbuf,
                                                    8192, 4096, 1024);

  // FF2 + residual: Xout = x1 + h@W_ff2 + b. Config B, 256 blocks.
  gemm_pipe<1, 4, 2, 4, 4><<<256, 512, 0, stream>>>(hbuf, wff2, b_ff2, x1, Xout, nullptr,
                                                    8192, 1024, 4096);
}